// Round 1
// baseline (542.420 us; speedup 1.0000x reference)
//
#include <hip/hip_runtime.h>
#include <hip/hip_bf16.h>
#include <stdint.h>

#define B_SZ 8192
#define D_SZ 1024
#define H_SZ 1024
#define O_SZ 512
#define E_SZ 8

typedef float f32x4 __attribute__((ext_vector_type(4)));
typedef __bf16 bf16x8 __attribute__((ext_vector_type(8)));

typedef __attribute__((address_space(1))) uint32_t gu32;
typedef __attribute__((address_space(3))) uint32_t lu32;

__device__ __forceinline__ unsigned short f2bf(float f) {
    union { __hip_bfloat16 h; unsigned short u; } c;
    c.h = __float2bfloat16(f);
    return c.u;
}
__device__ __forceinline__ float bf2f(unsigned short u) {
    union { float f; uint32_t u; } c;
    c.u = ((uint32_t)u) << 16;
    return c.f;
}

// ---------------- convert x (f32 -> bf16), 8 elems/thread ----------------
__global__ __launch_bounds__(256) void k_convert(const float* __restrict__ in,
                                                 unsigned short* __restrict__ out, int n8) {
    int i = blockIdx.x * 256 + threadIdx.x;
    if (i >= n8) return;
    const float4* p = (const float4*)in + (size_t)i * 2;
    float4 a = p[0], b = p[1];
    ushort4 lo, hi;
    lo.x = f2bf(a.x); lo.y = f2bf(a.y); lo.z = f2bf(a.z); lo.w = f2bf(a.w);
    hi.x = f2bf(b.x); hi.y = f2bf(b.y); hi.z = f2bf(b.z); hi.w = f2bf(b.w);
    ushort4* q = (ushort4*)out + (size_t)i * 2;
    q[0] = lo; q[1] = hi;
}

// ------- transpose+convert: in [E][R][C] f32 -> out [E][C][R] bf16 -------
__global__ __launch_bounds__(256) void k_transpose_convert(const float* __restrict__ in,
                                                           unsigned short* __restrict__ out,
                                                           int R, int C) {
    __shared__ float tile[32][33];
    const float* src = in + (size_t)blockIdx.z * R * C;
    unsigned short* dst = out + (size_t)blockIdx.z * R * C;
    int c0 = blockIdx.x * 32, r0 = blockIdx.y * 32;
    int tx = threadIdx.x, ty = threadIdx.y;   // block (32,8)
#pragma unroll
    for (int rr = ty; rr < 32; rr += 8)
        tile[rr][tx] = src[(size_t)(r0 + rr) * C + c0 + tx];
    __syncthreads();
#pragma unroll
    for (int rr = ty; rr < 32; rr += 8)
        dst[(size_t)(c0 + rr) * R + r0 + tx] = f2bf(tile[tx][rr]);
}

// ---------------- gates: 20 logits/row + 3 softmaxes ----------------
__global__ __launch_bounds__(64) void k_gates(const float* __restrict__ x,
                                              const float* __restrict__ Wg,
                                              const float* __restrict__ Wgs,
                                              float* __restrict__ g_all) {
    __shared__ float xs[D_SZ];
    __shared__ float logits[20];
    int b = blockIdx.x, lane = threadIdx.x;
    const float4* xr = (const float4*)(x + (size_t)b * D_SZ);
#pragma unroll
    for (int it = 0; it < D_SZ / 4 / 64; ++it)
        ((float4*)xs)[it * 64 + lane] = xr[it * 64 + lane];
    __syncthreads();
    if (lane < 20) {
        const float* w; int stride, col;
        if (lane < 12) { w = Wg + (lane / 6) * (D_SZ * 6); stride = 6; col = lane % 6; }
        else           { w = Wgs;                          stride = 8; col = lane - 12; }
        float s = 0.f;
#pragma unroll 4
        for (int d = 0; d < D_SZ; ++d)
            s += xs[d] * w[(size_t)d * stride + col];
        logits[lane] = s;
    }
    __syncthreads();
    if (lane < 3) {
        int base = (lane == 0) ? 0 : (lane == 1 ? 6 : 12);
        int cnt  = (lane == 2) ? 8 : 6;
        float m = -1e30f;
        for (int j = 0; j < cnt; ++j) m = fmaxf(m, logits[base + j]);
        float ex[8]; float sum = 0.f;
        for (int j = 0; j < cnt; ++j) { ex[j] = expf(logits[base + j] - m); sum += ex[j]; }
        float inv = 1.f / sum;
        for (int j = 0; j < cnt; ++j) g_all[(size_t)b * 20 + base + j] = ex[j] * inv;
    }
}

// ---------------- bf16 GEMM: C[M][N] = relu(A[M][K] * Bt[N][K]^T + bias) ----------------
// m97 structure: 128x128 tile, BK=64, 4 waves (2x2), global_load_lds w16, 2 barriers/K-step.
__global__ __launch_bounds__(256) void k_gemm_bt_relu(
    const unsigned short* __restrict__ A,
    const unsigned short* __restrict__ Bt,
    const float* __restrict__ bias,
    unsigned short* __restrict__ C,
    int M, int N, int K,
    long long sA, long long sB, long long sBias, long long sC, int e_base) {

    const int e = e_base + blockIdx.z;
    A    += (size_t)((long long)e * sA);
    Bt   += (size_t)((long long)e * sB);
    bias += (size_t)((long long)e * sBias);
    C    += (size_t)((long long)e * sC);

    const int tid = threadIdx.x;
    const int lane = tid & 63;
    const int wid = tid >> 6;
    const int wr = wid >> 1, wc = wid & 1;
    const int lr = lane & 15, lg = lane >> 4;

    const int m0 = blockIdx.y * 128;
    const int n0 = blockIdx.x * 128;

    __shared__ unsigned short As[128][64];
    __shared__ unsigned short Bs[128][64];

    f32x4 acc[4][4];
#pragma unroll
    for (int i = 0; i < 4; ++i)
#pragma unroll
        for (int j = 0; j < 4; ++j)
            acc[i][j] = f32x4{0.f, 0.f, 0.f, 0.f};

    for (int kt = 0; kt < K; kt += 64) {
#pragma unroll
        for (int it = 0; it < 4; ++it) {
            int lin = it * 2048 + tid * 8;     // bf16 element index in 128x64 tile
            int row = lin >> 6;
            int col = lin & 63;
            __builtin_amdgcn_global_load_lds(
                (gu32*)(A + (size_t)(m0 + row) * K + kt + col),
                (lu32*)(&As[0][0] + lin), 16, 0, 0);
            __builtin_amdgcn_global_load_lds(
                (gu32*)(Bt + (size_t)(n0 + row) * K + kt + col),
                (lu32*)(&Bs[0][0] + lin), 16, 0, 0);
        }
        __syncthreads();
#pragma unroll
        for (int kk = 0; kk < 64; kk += 32) {
            bf16x8 af[4], bfr[4];
#pragma unroll
            for (int i = 0; i < 4; ++i)
                af[i] = *(const bf16x8*)&As[wr * 64 + i * 16 + lr][kk + lg * 8];
#pragma unroll
            for (int j = 0; j < 4; ++j)
                bfr[j] = *(const bf16x8*)&Bs[wc * 64 + j * 16 + lr][kk + lg * 8];
#pragma unroll
            for (int i = 0; i < 4; ++i)
#pragma unroll
                for (int j = 0; j < 4; ++j)
                    acc[i][j] = __builtin_amdgcn_mfma_f32_16x16x32_bf16(af[i], bfr[j], acc[i][j], 0, 0, 0);
        }
        __syncthreads();
    }

    // epilogue: bias + relu + bf16 store.  C/D layout: col = lane&15, row = (lane>>4)*4 + reg
#pragma unroll
    for (int j = 0; j < 4; ++j) {
        int n = n0 + wc * 64 + j * 16 + lr;
        float bv = bias[n];
#pragma unroll
        for (int i = 0; i < 4; ++i) {
            int mbase = m0 + wr * 64 + i * 16 + lg * 4;
#pragma unroll
            for (int r = 0; r < 4; ++r) {
                float v = acc[i][j][r] + bv;
                v = fmaxf(v, 0.f);
                C[(size_t)(mbase + r) * N + n] = f2bf(v);
            }
        }
    }
}

// ---------------- combine: out[b][t][o] ----------------
__global__ __launch_bounds__(256) void k_combine(const unsigned short* __restrict__ eo,
                                                 const float* __restrict__ g_all,
                                                 float* __restrict__ out) {
    int idx = blockIdx.x * 256 + threadIdx.x;       // over B*O
    int b = idx >> 9;
    int o = idx & 511;
    const float* g = g_all + (size_t)b * 20;
    float v[E_SZ];
#pragma unroll
    for (int e = 0; e < E_SZ; ++e)
        v[e] = bf2f(eo[(size_t)e * (B_SZ * (size_t)O_SZ) + idx]);
    float o0 = g[0] * v[0] + g[1] * v[1] + g[2] * v[4] + g[3] * v[5] + g[4] * v[6] + g[5] * v[7];
    float o1 = g[6] * v[2] + g[7] * v[3] + g[8] * v[4] + g[9] * v[5] + g[10] * v[6] + g[11] * v[7];
    float o2 = 0.f;
#pragma unroll
    for (int e = 0; e < E_SZ; ++e) o2 += g[12 + e] * v[e];
    size_t ob = (size_t)b * (3 * O_SZ) + o;
    out[ob] = o0;
    out[ob + O_SZ] = o1;
    out[ob + 2 * O_SZ] = o2;
}

extern "C" void kernel_launch(void* const* d_in, const int* in_sizes, int n_in,
                              void* d_out, int out_size, void* d_ws, size_t ws_size,
                              hipStream_t stream) {
    const float* x   = (const float*)d_in[0];
    const float* W1  = (const float*)d_in[1];
    const float* b1  = (const float*)d_in[2];
    const float* W2  = (const float*)d_in[3];
    const float* b2  = (const float*)d_in[4];
    const float* Wg  = (const float*)d_in[5];
    const float* Wgs = (const float*)d_in[6];
    float* out = (float*)d_out;

    char* ws = (char*)d_ws;
    const size_t SZ_XBF  = (size_t)B_SZ * D_SZ * 2;           // 16 MB
    const size_t SZ_W1T  = (size_t)E_SZ * H_SZ * D_SZ * 2;    // 16 MB
    const size_t SZ_W2T  = (size_t)E_SZ * O_SZ * H_SZ * 2;    // 8 MB
    const size_t SZ_EO   = (size_t)E_SZ * B_SZ * O_SZ * 2;    // 64 MB
    const size_t SZ_G    = (size_t)B_SZ * 20 * 4;             // 640 KB
    const size_t SZ_HBIG = (size_t)E_SZ * B_SZ * H_SZ * 2;    // 128 MB
    const size_t SZ_HSML = (size_t)B_SZ * H_SZ * 2;           // 16 MB

    unsigned short* x_bf = (unsigned short*)ws;              ws += SZ_XBF;
    unsigned short* W1T  = (unsigned short*)ws;              ws += SZ_W1T;
    unsigned short* W2T  = (unsigned short*)ws;              ws += SZ_W2T;
    unsigned short* eo   = (unsigned short*)ws;              ws += SZ_EO;
    float* g_all         = (float*)ws;                       ws += SZ_G;
    unsigned short* h_buf = (unsigned short*)ws;

    const size_t fixed = SZ_XBF + SZ_W1T + SZ_W2T + SZ_EO + SZ_G;
    const bool big = ws_size >= fixed + SZ_HBIG;

    // 1) conversions
    k_convert<<<(B_SZ * D_SZ / 8 + 255) / 256, 256, 0, stream>>>(x, x_bf, B_SZ * D_SZ / 8);
    dim3 tb(32, 8);
    k_transpose_convert<<<dim3(H_SZ / 32, D_SZ / 32, E_SZ), tb, 0, stream>>>(W1, W1T, D_SZ, H_SZ);
    k_transpose_convert<<<dim3(O_SZ / 32, H_SZ / 32, E_SZ), tb, 0, stream>>>(W2, W2T, H_SZ, O_SZ);

    // 2) gates
    k_gates<<<B_SZ, 64, 0, stream>>>(x, Wg, Wgs, g_all);

    // 3) expert GEMMs
    if (big) {
        k_gemm_bt_relu<<<dim3(H_SZ / 128, B_SZ / 128, E_SZ), 256, 0, stream>>>(
            x_bf, W1T, b1, h_buf, B_SZ, H_SZ, D_SZ,
            0LL, (long long)H_SZ * D_SZ, (long long)H_SZ, (long long)B_SZ * H_SZ, 0);
        k_gemm_bt_relu<<<dim3(O_SZ / 128, B_SZ / 128, E_SZ), 256, 0, stream>>>(
            h_buf, W2T, b2, eo, B_SZ, O_SZ, H_SZ,
            (long long)B_SZ * H_SZ, (long long)O_SZ * H_SZ, (long long)O_SZ, (long long)B_SZ * O_SZ, 0);
    } else {
        for (int e = 0; e < E_SZ; ++e) {
            k_gemm_bt_relu<<<dim3(H_SZ / 128, B_SZ / 128, 1), 256, 0, stream>>>(
                x_bf, W1T, b1, h_buf, B_SZ, H_SZ, D_SZ,
                0LL, (long long)H_SZ * D_SZ, (long long)H_SZ, 0LL, e);
            k_gemm_bt_relu<<<dim3(O_SZ / 128, B_SZ / 128, 1), 256, 0, stream>>>(
                h_buf, W2T, b2, eo, B_SZ, O_SZ, H_SZ,
                0LL, (long long)O_SZ * H_SZ, (long long)O_SZ, (long long)B_SZ * O_SZ, e);
        }
    }

    // 4) combine
    k_combine<<<(B_SZ * O_SZ) / 256, 256, 0, stream>>>(eo, g_all, out);
}

// Round 3
// 344.271 us; speedup vs baseline: 1.5756x; 1.5756x over previous
//
#include <hip/hip_runtime.h>
#include <hip/hip_bf16.h>
#include <stdint.h>

#define B_SZ 8192
#define D_SZ 1024
#define H_SZ 1024
#define O_SZ 512
#define E_SZ 8

typedef float f32x4 __attribute__((ext_vector_type(4)));
typedef __bf16 bf16x8 __attribute__((ext_vector_type(8)));

typedef __attribute__((address_space(1))) uint32_t gu32;
typedef __attribute__((address_space(3))) uint32_t lu32;

__device__ __forceinline__ unsigned short f2bf(float f) {
    union { __hip_bfloat16 h; unsigned short u; } c;
    c.h = __float2bfloat16(f);
    return c.u;
}
__device__ __forceinline__ float bf2f(unsigned short u) {
    union { float f; uint32_t u; } c;
    c.u = ((uint32_t)u) << 16;
    return c.f;
}

// ---------------- convert x (f32 -> bf16), 8 elems/thread ----------------
__global__ __launch_bounds__(256) void k_convert(const float* __restrict__ in,
                                                 unsigned short* __restrict__ out, int n8) {
    int i = blockIdx.x * 256 + threadIdx.x;
    if (i >= n8) return;
    const float4* p = (const float4*)in + (size_t)i * 2;
    float4 a = p[0], b = p[1];
    ushort4 lo, hi;
    lo.x = f2bf(a.x); lo.y = f2bf(a.y); lo.z = f2bf(a.z); lo.w = f2bf(a.w);
    hi.x = f2bf(b.x); hi.y = f2bf(b.y); hi.z = f2bf(b.z); hi.w = f2bf(b.w);
    ushort4* q = (ushort4*)out + (size_t)i * 2;
    q[0] = lo; q[1] = hi;
}

// ------- transpose+convert: in [E][R][C] f32 -> out [E][C][R] bf16 -------
__global__ __launch_bounds__(256) void k_transpose_convert(const float* __restrict__ in,
                                                           unsigned short* __restrict__ out,
                                                           int R, int C) {
    __shared__ float tile[32][33];
    const float* src = in + (size_t)blockIdx.z * R * C;
    unsigned short* dst = out + (size_t)blockIdx.z * R * C;
    int c0 = blockIdx.x * 32, r0 = blockIdx.y * 32;
    int tx = threadIdx.x, ty = threadIdx.y;   // block (32,8)
#pragma unroll
    for (int rr = ty; rr < 32; rr += 8)
        tile[rr][tx] = src[(size_t)(r0 + rr) * C + c0 + tx];
    __syncthreads();
#pragma unroll
    for (int rr = ty; rr < 32; rr += 8)
        dst[(size_t)(c0 + rr) * R + r0 + tx] = f2bf(tile[tx][rr]);
}

// ---------------- gates: wave-parallel 20 logits/row + 3 softmaxes ----------------
__global__ __launch_bounds__(256) void k_gates(const float* __restrict__ x,
                                               const float* __restrict__ Wg,
                                               const float* __restrict__ Wgs,
                                               float* __restrict__ g_all) {
    const int wv = threadIdx.x >> 6;
    const int lane = threadIdx.x & 63;
    const int b = blockIdx.x * 4 + wv;
    const float* xr = x + (size_t)b * D_SZ;
    float acc[20];
#pragma unroll
    for (int j = 0; j < 20; ++j) acc[j] = 0.f;
    for (int d = lane; d < D_SZ; d += 64) {
        float xv = xr[d];
        const float* w0 = Wg + (size_t)d * 6;
        const float* w1 = Wg + (size_t)D_SZ * 6 + (size_t)d * 6;
        const float* ws = Wgs + (size_t)d * 8;
#pragma unroll
        for (int j = 0; j < 6; ++j) acc[j] += xv * w0[j];
#pragma unroll
        for (int j = 0; j < 6; ++j) acc[6 + j] += xv * w1[j];
#pragma unroll
        for (int j = 0; j < 8; ++j) acc[12 + j] += xv * ws[j];
    }
#pragma unroll
    for (int j = 0; j < 20; ++j) {
        float v = acc[j];
#pragma unroll
        for (int s = 32; s > 0; s >>= 1) v += __shfl_down(v, s, 64);
        acc[j] = v;
    }
    if (lane == 0) {
        float* g = g_all + (size_t)b * 20;
#pragma unroll
        for (int t = 0; t < 3; ++t) {
            int base = (t == 0) ? 0 : (t == 1 ? 6 : 12);
            int cnt  = (t == 2) ? 8 : 6;
            float m = -1e30f;
            for (int j = 0; j < cnt; ++j) m = fmaxf(m, acc[base + j]);
            float ex[8]; float sum = 0.f;
            for (int j = 0; j < cnt; ++j) { ex[j] = __expf(acc[base + j] - m); sum += ex[j]; }
            float inv = 1.f / sum;
            for (int j = 0; j < cnt; ++j) g[base + j] = ex[j] * inv;
        }
    }
}

// ---------------- 256x256 deep-pipelined bf16 GEMM, BK=32, 4 LDS buffers ----------------
// C[M][N] = relu(A[M][K] * Bt[N][K]^T + bias), bf16 in/out, f32 accum.
// 512 threads = 8 waves (2 M x 4 N); per-wave 128x64 output, acc[8][4] f32x4.
// LDS 128 KiB = 4 round-robin K-tile buffers x 32 KiB { A 256x32, B 256x32 }.
// Race-free by construction: stages during tile t target buf (t+3)%4; live buf is t%4.
// Swizzle: physical 16B block = blk ^ ((row>>1)&3) -> 2-way (free) bank aliasing.
// Counted vmcnt(8) boundaries (tail 4, 0); never drains to 0 in steady state.
__global__ __launch_bounds__(512, 2) void k_gemm4(
    const unsigned short* __restrict__ A,
    const unsigned short* __restrict__ Bt,
    const float* __restrict__ bias,
    unsigned short* __restrict__ C,
    int M, int N, int K,
    long long sA, long long sB, long long sBias, long long sC, int e_base) {

    const int tid = threadIdx.x;
    const int lane = tid & 63, wid = tid >> 6;
    const int wr = wid >> 2, wc = wid & 3;       // 2 x 4 wave grid
    const int lr = lane & 15, lg = lane >> 4;

    // bijective XCD swizzle on flat grid (nwg % 8 == 0 for all launches here)
    const int nwg = gridDim.x;
    const int wg = blockIdx.x;
    const int swz = (wg & 7) * (nwg >> 3) + (wg >> 3);
    const int nx = N >> 8;
    const int my = M >> 8;
    const int bx = swz % nx;
    const int t1 = swz / nx;
    const int by = t1 % my;
    const int e  = t1 / my + e_base;

    A    += (size_t)((long long)e * sA);
    Bt   += (size_t)((long long)e * sB);
    bias += (size_t)((long long)e * sBias);
    C    += (size_t)((long long)e * sC);

    const int m0 = by * 256, n0 = bx * 256;

    __shared__ __align__(16) unsigned short lds[65536];   // 128 KiB
    char* ldsb = (char*)lds;

    // staging: 512 thr x 16 B = one 8 KiB half (128 rows x 32 cols bf16), linear dest.
    // physical (row, blk) holds source col-block blk ^ ((row>>1)&3)  (blk = 8-elem group)
    const int srow = tid >> 2;
    const int scol = (((tid & 3) ^ ((tid >> 3) & 3)) * 8);
    const int sdst = tid * 16;

    auto stageA = [&](int t) {
        const int bb = (t & 3) * 32768;
        const unsigned short* s0 = A + (size_t)(m0 + srow) * K + (t << 5) + scol;
        __builtin_amdgcn_global_load_lds((gu32*)s0, (lu32*)(ldsb + bb + sdst), 16, 0, 0);
        __builtin_amdgcn_global_load_lds((gu32*)(s0 + (size_t)128 * K),
                                         (lu32*)(ldsb + bb + 8192 + sdst), 16, 0, 0);
    };
    auto stageB = [&](int t) {
        const int bb = (t & 3) * 32768 + 16384;
        const unsigned short* s0 = Bt + (size_t)(n0 + srow) * K + (t << 5) + scol;
        __builtin_amdgcn_global_load_lds((gu32*)s0, (lu32*)(ldsb + bb + sdst), 16, 0, 0);
        __builtin_amdgcn_global_load_lds((gu32*)(s0 + (size_t)128 * K),
                                         (lu32*)(ldsb + bb + 8192 + sdst), 16, 0, 0);
    };

    // fragment read constants (byte offsets); swizzle term depends only on lr
    const int cblk = (lg ^ ((lr >> 1) & 3)) * 16;
    const int aoff = wr * 8192 + lr * 64 + cblk;
    const int boff = 16384 + (wc >> 1) * 8192 + (wc & 1) * 4096 + lr * 64 + cblk;

    f32x4 acc[8][4];
#pragma unroll
    for (int i = 0; i < 8; ++i)
#pragma unroll
        for (int j = 0; j < 4; ++j)
            acc[i][j] = f32x4{0.f, 0.f, 0.f, 0.f};

    const int NT = K >> 5;

    // prologue: tiles 0,1,2 staged; wait tile 0 landed (8 = tiles 1,2 in flight)
    stageA(0); stageB(0); stageA(1); stageB(1); stageA(2); stageB(2);
    asm volatile("s_waitcnt vmcnt(8)" ::: "memory");
    asm volatile("s_barrier" ::: "memory");

    for (int t = 0; t < NT; ++t) {
        const int bb = (t & 3) * 32768;

        // ---- phase A: acc rows 0-3, all 4 col-blocks ----
        bf16x8 bq[4], af[4];
#pragma unroll
        for (int j = 0; j < 4; ++j)
            bq[j] = *(const bf16x8*)(ldsb + bb + boff + j * 1024);
#pragma unroll
        for (int i = 0; i < 4; ++i)
            af[i] = *(const bf16x8*)(ldsb + bb + aoff + i * 1024);
        if (t + 3 < NT) stageA(t + 3);
        asm volatile("s_barrier" ::: "memory");
        __builtin_amdgcn_s_setprio(1);
#pragma unroll
        for (int i = 0; i < 4; ++i)
#pragma unroll
            for (int j = 0; j < 4; ++j)
                acc[i][j] = __builtin_amdgcn_mfma_f32_16x16x32_bf16(af[i], bq[j], acc[i][j], 0, 0, 0);
        __builtin_amdgcn_s_setprio(0);
        asm volatile("s_barrier" ::: "memory");

        // ---- phase B: acc rows 4-7 (bq reused from registers) ----
        bf16x8 ag[4];
#pragma unroll
        for (int i = 0; i < 4; ++i)
            ag[i] = *(const bf16x8*)(ldsb + bb + aoff + (4 + i) * 1024);
        if (t + 3 < NT) stageB(t + 3);
        asm volatile("s_barrier" ::: "memory");
        __builtin_amdgcn_s_setprio(1);
#pragma unroll
        for (int i = 0; i < 4; ++i)
#pragma unroll
            for (int j = 0; j < 4; ++j)
                acc[4 + i][j] = __builtin_amdgcn_mfma_f32_16x16x32_bf16(ag[i], bq[j], acc[4 + i][j], 0, 0, 0);
        __builtin_amdgcn_s_setprio(0);
        // boundary: ensure tile t+1 landed; keep later tiles in flight (counted, not 0)
        if (t < NT - 3)       { asm volatile("s_waitcnt vmcnt(8)" ::: "memory"); }
        else if (t == NT - 3) { asm volatile("s_waitcnt vmcnt(4)" ::: "memory"); }
        else if (t == NT - 2) { asm volatile("s_waitcnt vmcnt(0)" ::: "memory"); }
        asm volatile("s_barrier" ::: "memory");
    }

    // ---- epilogue: bias + relu + bf16 store (C/D: col=lr, row=lg*4+reg) ----
#pragma unroll
    for (int j = 0; j < 4; ++j) {
        const int n = n0 + wc * 64 + j * 16 + lr;
        const float bv = bias[n];
#pragma unroll
        for (int i = 0; i < 8; ++i) {
            const int mb = m0 + wr * 128 + i * 16 + lg * 4;
#pragma unroll
            for (int r = 0; r < 4; ++r) {
                float v = fmaxf(acc[i][j][r] + bv, 0.f);
                C[(size_t)(mb + r) * N + n] = f2bf(v);
            }
        }
    }
}

// ---------------- combine: out[b][t][o] ----------------
__global__ __launch_bounds__(256) void k_combine(const unsigned short* __restrict__ eo,
                                                 const float* __restrict__ g_all,
                                                 float* __restrict__ out) {
    int idx = blockIdx.x * 256 + threadIdx.x;       // over B*O
    int b = idx >> 9;
    int o = idx & 511;
    const float* g = g_all + (size_t)b * 20;
    float v[E_SZ];
#pragma unroll
    for (int e = 0; e < E_SZ; ++e)
        v[e] = bf2f(eo[(size_t)e * (B_SZ * (size_t)O_SZ) + idx]);
    float o0 = g[0] * v[0] + g[1] * v[1] + g[2] * v[4] + g[3] * v[5] + g[4] * v[6] + g[5] * v[7];
    float o1 = g[6] * v[2] + g[7] * v[3] + g[8] * v[4] + g[9] * v[5] + g[10] * v[6] + g[11] * v[7];
    float o2 = 0.f;
#pragma unroll
    for (int e = 0; e < E_SZ; ++e) o2 += g[12 + e] * v[e];
    size_t ob = (size_t)b * (3 * O_SZ) + o;
    out[ob] = o0;
    out[ob + O_SZ] = o1;
    out[ob + 2 * O_SZ] = o2;
}

extern "C" void kernel_launch(void* const* d_in, const int* in_sizes, int n_in,
                              void* d_out, int out_size, void* d_ws, size_t ws_size,
                              hipStream_t stream) {
    const float* x   = (const float*)d_in[0];
    const float* W1  = (const float*)d_in[1];
    const float* b1  = (const float*)d_in[2];
    const float* W2  = (const float*)d_in[3];
    const float* b2  = (const float*)d_in[4];
    const float* Wg  = (const float*)d_in[5];
    const float* Wgs = (const float*)d_in[6];
    float* out = (float*)d_out;

    char* ws = (char*)d_ws;
    const size_t SZ_XBF  = (size_t)B_SZ * D_SZ * 2;           // 16 MB
    const size_t SZ_W1T  = (size_t)E_SZ * H_SZ * D_SZ * 2;    // 16 MB
    const size_t SZ_W2T  = (size_t)E_SZ * O_SZ * H_SZ * 2;    // 8 MB
    const size_t SZ_EO   = (size_t)E_SZ * B_SZ * O_SZ * 2;    // 64 MB
    const size_t SZ_G    = (size_t)B_SZ * 20 * 4;             // 640 KB
    const size_t SZ_HBIG = (size_t)E_SZ * B_SZ * H_SZ * 2;    // 128 MB

    unsigned short* x_bf = (unsigned short*)ws;              ws += SZ_XBF;
    unsigned short* W1T  = (unsigned short*)ws;              ws += SZ_W1T;
    unsigned short* W2T  = (unsigned short*)ws;              ws += SZ_W2T;
    unsigned short* eo   = (unsigned short*)ws;              ws += SZ_EO;
    float* g_all         = (float*)ws;                       ws += SZ_G;
    unsigned short* h_buf = (unsigned short*)ws;

    const size_t fixed = SZ_XBF + SZ_W1T + SZ_W2T + SZ_EO + SZ_G;
    const bool big = ws_size >= fixed + SZ_HBIG;

    // 1) conversions
    k_convert<<<(B_SZ * D_SZ / 8 + 255) / 256, 256, 0, stream>>>(x, x_bf, B_SZ * D_SZ / 8);
    dim3 tb(32, 8);
    k_transpose_convert<<<dim3(H_SZ / 32, D_SZ / 32, E_SZ), tb, 0, stream>>>(W1, W1T, D_SZ, H_SZ);
    k_transpose_convert<<<dim3(O_SZ / 32, H_SZ / 32, E_SZ), tb, 0, stream>>>(W2, W2T, H_SZ, O_SZ);

    // 2) gates
    k_gates<<<B_SZ / 4, 256, 0, stream>>>(x, Wg, Wgs, g_all);

    // 3) expert GEMMs (256x256 tiles; flat 1D grids, all % 8 == 0)
    if (big) {
        k_gemm4<<<(H_SZ / 256) * (B_SZ / 256) * E_SZ, 512, 0, stream>>>(
            x_bf, W1T, b1, h_buf, B_SZ, H_SZ, D_SZ,
            0LL, (long long)H_SZ * D_SZ, (long long)H_SZ, (long long)B_SZ * H_SZ, 0);
        k_gemm4<<<(O_SZ / 256) * (B_SZ / 256) * E_SZ, 512, 0, stream>>>(
            h_buf, W2T, b2, eo, B_SZ, O_SZ, H_SZ,
            (long long)B_SZ * H_SZ, (long long)O_SZ * H_SZ, (long long)O_SZ, (long long)B_SZ * O_SZ, 0);
    } else {
        for (int e = 0; e < E_SZ; ++e) {
            k_gemm4<<<(H_SZ / 256) * (B_SZ / 256), 512, 0, stream>>>(
                x_bf, W1T, b1, h_buf, B_SZ, H_SZ, D_SZ,
                0LL, (long long)H_SZ * D_SZ, (long long)H_SZ, 0LL, e);
            k_gemm4<<<(O_SZ / 256) * (B_SZ / 256), 512, 0, stream>>>(
                h_buf, W2T, b2, eo, B_SZ, O_SZ, H_SZ,
                0LL, (long long)O_SZ * H_SZ, (long long)O_SZ, (long long)B_SZ * O_SZ, e);
        }
    }

    // 4) combine
    k_combine<<<(B_SZ * O_SZ) / 256, 256, 0, stream>>>(eo, g_all, out);
}

// Round 4
// 311.274 us; speedup vs baseline: 1.7426x; 1.1060x over previous
//
#include <hip/hip_runtime.h>
#include <hip/hip_bf16.h>
#include <stdint.h>

#define B_SZ 8192
#define D_SZ 1024
#define H_SZ 1024
#define O_SZ 512
#define E_SZ 8

typedef float f32x4 __attribute__((ext_vector_type(4)));
typedef __bf16 bf16x8 __attribute__((ext_vector_type(8)));

typedef __attribute__((address_space(1))) uint32_t gu32;
typedef __attribute__((address_space(3))) uint32_t lu32;

__device__ __forceinline__ unsigned short f2bf(float f) {
    union { __hip_bfloat16 h; unsigned short u; } c;
    c.h = __float2bfloat16(f);
    return c.u;
}
__device__ __forceinline__ float bf2f(unsigned short u) {
    union { float f; uint32_t u; } c;
    c.u = ((uint32_t)u) << 16;
    return c.f;
}

// ---------------- convert x (f32 -> bf16), 8 elems/thread ----------------
__global__ __launch_bounds__(256) void k_convert(const float* __restrict__ in,
                                                 unsigned short* __restrict__ out, int n8) {
    int i = blockIdx.x * 256 + threadIdx.x;
    if (i >= n8) return;
    const float4* p = (const float4*)in + (size_t)i * 2;
    float4 a = p[0], b = p[1];
    ushort4 lo, hi;
    lo.x = f2bf(a.x); lo.y = f2bf(a.y); lo.z = f2bf(a.z); lo.w = f2bf(a.w);
    hi.x = f2bf(b.x); hi.y = f2bf(b.y); hi.z = f2bf(b.z); hi.w = f2bf(b.w);
    ushort4* q = (ushort4*)out + (size_t)i * 2;
    q[0] = lo; q[1] = hi;
}

// ------- transpose+convert: in [E][R][C] f32 -> out [E][C][R] bf16 -------
// 64x64 tile: dst writes are 64 consecutive ushorts = 128 B full lines.
__global__ __launch_bounds__(512) void k_transpose_convert(const float* __restrict__ in,
                                                           unsigned short* __restrict__ out,
                                                           int R, int C) {
    __shared__ float tile[64][65];
    const float* src = in + (size_t)blockIdx.z * R * C;
    unsigned short* dst = out + (size_t)blockIdx.z * R * C;
    int c0 = blockIdx.x * 64, r0 = blockIdx.y * 64;
    int tx = threadIdx.x, ty = threadIdx.y;   // block (64,8)
#pragma unroll
    for (int rr = ty; rr < 64; rr += 8)
        tile[rr][tx] = src[(size_t)(r0 + rr) * C + c0 + tx];
    __syncthreads();
#pragma unroll
    for (int rr = ty; rr < 64; rr += 8)
        dst[(size_t)(c0 + rr) * R + r0 + tx] = f2bf(tile[tx][rr]);
}

// ---------------- gates: wave-parallel 20 logits/row + 3 softmaxes ----------------
__global__ __launch_bounds__(256) void k_gates(const float* __restrict__ x,
                                               const float* __restrict__ Wg,
                                               const float* __restrict__ Wgs,
                                               float* __restrict__ g_all) {
    const int wv = threadIdx.x >> 6;
    const int lane = threadIdx.x & 63;
    const int b = blockIdx.x * 4 + wv;
    const float* xr = x + (size_t)b * D_SZ;
    float acc[20];
#pragma unroll
    for (int j = 0; j < 20; ++j) acc[j] = 0.f;
    for (int d = lane; d < D_SZ; d += 64) {
        float xv = xr[d];
        const float* w0 = Wg + (size_t)d * 6;
        const float* w1 = Wg + (size_t)D_SZ * 6 + (size_t)d * 6;
        const float* ws = Wgs + (size_t)d * 8;
#pragma unroll
        for (int j = 0; j < 6; ++j) acc[j] += xv * w0[j];
#pragma unroll
        for (int j = 0; j < 6; ++j) acc[6 + j] += xv * w1[j];
#pragma unroll
        for (int j = 0; j < 8; ++j) acc[12 + j] += xv * ws[j];
    }
#pragma unroll
    for (int j = 0; j < 20; ++j) {
        float v = acc[j];
#pragma unroll
        for (int s = 32; s > 0; s >>= 1) v += __shfl_down(v, s, 64);
        acc[j] = v;
    }
    if (lane == 0) {
        float* g = g_all + (size_t)b * 20;
#pragma unroll
        for (int t = 0; t < 3; ++t) {
            int base = (t == 0) ? 0 : (t == 1 ? 6 : 12);
            int cnt  = (t == 2) ? 8 : 6;
            float m = -1e30f;
            for (int j = 0; j < cnt; ++j) m = fmaxf(m, acc[base + j]);
            float ex[8]; float sum = 0.f;
            for (int j = 0; j < cnt; ++j) { ex[j] = __expf(acc[base + j] - m); sum += ex[j]; }
            float inv = 1.f / sum;
            for (int j = 0; j < cnt; ++j) g[base + j] = ex[j] * inv;
        }
    }
}

// ---------------- 256x256 deep-pipelined bf16 GEMM, BK=32, 4 LDS buffers ----------------
// C[M][N] = relu(A[M][K] * Bt[N][K]^T + bias), bf16 in/out, f32 accum.
// 512 threads = 8 waves (2 M x 4 N); per-wave 128x64 output, acc[8][4] f32x4.
// LDS 128 KiB = 4 round-robin K-tile buffers x 32 KiB { A 256x32, B 256x32 }.
// Race-free: stages during tile t target buf (t+3)%4; live buf is t%4.
// Swizzle: physical 16B block = blk ^ ((row>>1)&3) -> 2-way (free) bank aliasing.
// Counted vmcnt(8) boundaries (tail 4, 0). Epilogue: LDS-staged coalesced
// dwordx4 stores (full 128B lines; kills the 2.4x write amplification).
__global__ __launch_bounds__(512, 2) void k_gemm4(
    const unsigned short* __restrict__ A,
    const unsigned short* __restrict__ Bt,
    const float* __restrict__ bias,
    unsigned short* __restrict__ C,
    int M, int N, int K,
    long long sA, long long sB, long long sBias, long long sC, int e_base) {

    const int tid = threadIdx.x;
    const int lane = tid & 63, wid = tid >> 6;
    const int wr = wid >> 2, wc = wid & 3;       // 2 x 4 wave grid
    const int lr = lane & 15, lg = lane >> 4;

    // bijective XCD swizzle on flat grid (nwg % 8 == 0 for all launches here)
    const int nwg = gridDim.x;
    const int wg = blockIdx.x;
    const int swz = (wg & 7) * (nwg >> 3) + (wg >> 3);
    const int nx = N >> 8;
    const int my = M >> 8;
    const int bx = swz % nx;
    const int t1 = swz / nx;
    const int by = t1 % my;
    const int e  = t1 / my + e_base;

    A    += (size_t)((long long)e * sA);
    Bt   += (size_t)((long long)e * sB);
    bias += (size_t)((long long)e * sBias);
    C    += (size_t)((long long)e * sC);

    const int m0 = by * 256, n0 = bx * 256;

    __shared__ __align__(16) unsigned short lds[65536];   // 128 KiB
    char* ldsb = (char*)lds;

    // staging: 512 thr x 16 B = one 8 KiB half (128 rows x 32 cols bf16), linear dest.
    // physical (row, blk) holds source col-block blk ^ ((row>>1)&3)  (blk = 8-elem group)
    const int srow = tid >> 2;
    const int scol = (((tid & 3) ^ ((tid >> 3) & 3)) * 8);
    const int sdst = tid * 16;

    auto stageA = [&](int t) {
        const int bb = (t & 3) * 32768;
        const unsigned short* s0 = A + (size_t)(m0 + srow) * K + (t << 5) + scol;
        __builtin_amdgcn_global_load_lds((gu32*)s0, (lu32*)(ldsb + bb + sdst), 16, 0, 0);
        __builtin_amdgcn_global_load_lds((gu32*)(s0 + (size_t)128 * K),
                                         (lu32*)(ldsb + bb + 8192 + sdst), 16, 0, 0);
    };
    auto stageB = [&](int t) {
        const int bb = (t & 3) * 32768 + 16384;
        const unsigned short* s0 = Bt + (size_t)(n0 + srow) * K + (t << 5) + scol;
        __builtin_amdgcn_global_load_lds((gu32*)s0, (lu32*)(ldsb + bb + sdst), 16, 0, 0);
        __builtin_amdgcn_global_load_lds((gu32*)(s0 + (size_t)128 * K),
                                         (lu32*)(ldsb + bb + 8192 + sdst), 16, 0, 0);
    };

    // fragment read constants (byte offsets); swizzle term depends only on lr
    const int cblk = (lg ^ ((lr >> 1) & 3)) * 16;
    const int aoff = wr * 8192 + lr * 64 + cblk;
    const int boff = 16384 + (wc >> 1) * 8192 + (wc & 1) * 4096 + lr * 64 + cblk;

    f32x4 acc[8][4];
#pragma unroll
    for (int i = 0; i < 8; ++i)
#pragma unroll
        for (int j = 0; j < 4; ++j)
            acc[i][j] = f32x4{0.f, 0.f, 0.f, 0.f};

    const int NT = K >> 5;

    // prologue: tiles 0,1,2 staged; wait tile 0 landed (8 = tiles 1,2 in flight)
    stageA(0); stageB(0); stageA(1); stageB(1); stageA(2); stageB(2);
    asm volatile("s_waitcnt vmcnt(8)" ::: "memory");
    asm volatile("s_barrier" ::: "memory");

    for (int t = 0; t < NT; ++t) {
        const int bb = (t & 3) * 32768;

        // ---- phase A: acc rows 0-3, all 4 col-blocks ----
        bf16x8 bq[4], af[4];
#pragma unroll
        for (int j = 0; j < 4; ++j)
            bq[j] = *(const bf16x8*)(ldsb + bb + boff + j * 1024);
#pragma unroll
        for (int i = 0; i < 4; ++i)
            af[i] = *(const bf16x8*)(ldsb + bb + aoff + i * 1024);
        if (t + 3 < NT) stageA(t + 3);
        asm volatile("s_barrier" ::: "memory");
        __builtin_amdgcn_s_setprio(1);
#pragma unroll
        for (int i = 0; i < 4; ++i)
#pragma unroll
            for (int j = 0; j < 4; ++j)
                acc[i][j] = __builtin_amdgcn_mfma_f32_16x16x32_bf16(af[i], bq[j], acc[i][j], 0, 0, 0);
        __builtin_amdgcn_s_setprio(0);
        asm volatile("s_barrier" ::: "memory");

        // ---- phase B: acc rows 4-7 (bq reused from registers) ----
        bf16x8 ag[4];
#pragma unroll
        for (int i = 0; i < 4; ++i)
            ag[i] = *(const bf16x8*)(ldsb + bb + aoff + (4 + i) * 1024);
        if (t + 3 < NT) stageB(t + 3);
        asm volatile("s_barrier" ::: "memory");
        __builtin_amdgcn_s_setprio(1);
#pragma unroll
        for (int i = 0; i < 4; ++i)
#pragma unroll
            for (int j = 0; j < 4; ++j)
                acc[4 + i][j] = __builtin_amdgcn_mfma_f32_16x16x32_bf16(ag[i], bq[j], acc[4 + i][j], 0, 0, 0);
        __builtin_amdgcn_s_setprio(0);
        // boundary: ensure tile t+1 landed; keep later tiles in flight (counted, not 0)
        if (t < NT - 3)       { asm volatile("s_waitcnt vmcnt(8)" ::: "memory"); }
        else if (t == NT - 3) { asm volatile("s_waitcnt vmcnt(4)" ::: "memory"); }
        else if (t == NT - 2) { asm volatile("s_waitcnt vmcnt(0)" ::: "memory"); }
        asm volatile("s_barrier" ::: "memory");
    }

    // ---- epilogue: bias + relu -> LDS-staged bf16 tile -> coalesced dwordx4 stores ----
    // LDS is dead after the final barrier (all gload_lds drained at t==NT-2, all
    // ds_reads consumed before the last s_barrier). Ct layout: [256][256] bf16 = 128 KiB.
    unsigned short* ct = (unsigned short*)ldsb;
#pragma unroll
    for (int j = 0; j < 4; ++j) {
        const int nn = wc * 64 + j * 16 + lr;
        const float bv = bias[n0 + nn];
#pragma unroll
        for (int i = 0; i < 8; ++i) {
            const int mb = wr * 128 + i * 16 + lg * 4;
#pragma unroll
            for (int r = 0; r < 4; ++r) {
                float v = fmaxf(acc[i][j][r] + bv, 0.f);
                ct[(size_t)(mb + r) * 256 + nn] = f2bf(v);
            }
        }
    }
    __syncthreads();
#pragma unroll
    for (int it = 0; it < 16; ++it) {
        const int row = it * 16 + (tid >> 5);
        const int colE = (tid & 31) * 8;
        *(int4*)(&C[(size_t)(m0 + row) * N + n0 + colE]) =
            *(const int4*)(ldsb + it * 8192 + (size_t)tid * 16);
    }
}

// ---------------- combine: out[b][t][o], 4 o's per thread ----------------
__global__ __launch_bounds__(256) void k_combine(const unsigned short* __restrict__ eo,
                                                 const float* __restrict__ g_all,
                                                 float* __restrict__ out) {
    int idx4 = blockIdx.x * 256 + threadIdx.x;    // over B*O/4
    int b = idx4 >> 7;                            // O/4 = 128
    int o4 = (idx4 & 127) * 4;
    const float* g = g_all + (size_t)b * 20;
    float v[E_SZ][4];
#pragma unroll
    for (int e = 0; e < E_SZ; ++e) {
        ushort4 u = *(const ushort4*)(eo + (size_t)e * B_SZ * O_SZ + (size_t)b * O_SZ + o4);
        v[e][0] = bf2f(u.x); v[e][1] = bf2f(u.y); v[e][2] = bf2f(u.z); v[e][3] = bf2f(u.w);
    }
    float4 r0, r1, r2;
    float* p0 = (float*)&r0; float* p1 = (float*)&r1; float* p2 = (float*)&r2;
#pragma unroll
    for (int c = 0; c < 4; ++c) {
        p0[c] = g[0] * v[0][c] + g[1] * v[1][c] + g[2] * v[4][c] + g[3] * v[5][c]
              + g[4] * v[6][c] + g[5] * v[7][c];
        p1[c] = g[6] * v[2][c] + g[7] * v[3][c] + g[8] * v[4][c] + g[9] * v[5][c]
              + g[10] * v[6][c] + g[11] * v[7][c];
        float s = 0.f;
#pragma unroll
        for (int e = 0; e < E_SZ; ++e) s += g[12 + e] * v[e][c];
        p2[c] = s;
    }
    size_t ob = (size_t)b * (3 * O_SZ) + o4;
    *(float4*)(out + ob) = r0;
    *(float4*)(out + ob + O_SZ) = r1;
    *(float4*)(out + ob + 2 * O_SZ) = r2;
}

extern "C" void kernel_launch(void* const* d_in, const int* in_sizes, int n_in,
                              void* d_out, int out_size, void* d_ws, size_t ws_size,
                              hipStream_t stream) {
    const float* x   = (const float*)d_in[0];
    const float* W1  = (const float*)d_in[1];
    const float* b1  = (const float*)d_in[2];
    const float* W2  = (const float*)d_in[3];
    const float* b2  = (const float*)d_in[4];
    const float* Wg  = (const float*)d_in[5];
    const float* Wgs = (const float*)d_in[6];
    float* out = (float*)d_out;

    char* ws = (char*)d_ws;
    const size_t SZ_XBF  = (size_t)B_SZ * D_SZ * 2;           // 16 MB
    const size_t SZ_W1T  = (size_t)E_SZ * H_SZ * D_SZ * 2;    // 16 MB
    const size_t SZ_W2T  = (size_t)E_SZ * O_SZ * H_SZ * 2;    // 8 MB
    const size_t SZ_EO   = (size_t)E_SZ * B_SZ * O_SZ * 2;    // 64 MB
    const size_t SZ_G    = (size_t)B_SZ * 20 * 4;             // 640 KB
    const size_t SZ_HBIG = (size_t)E_SZ * B_SZ * H_SZ * 2;    // 128 MB

    unsigned short* x_bf = (unsigned short*)ws;              ws += SZ_XBF;
    unsigned short* W1T  = (unsigned short*)ws;              ws += SZ_W1T;
    unsigned short* W2T  = (unsigned short*)ws;              ws += SZ_W2T;
    unsigned short* eo   = (unsigned short*)ws;              ws += SZ_EO;
    float* g_all         = (float*)ws;                       ws += SZ_G;
    unsigned short* h_buf = (unsigned short*)ws;

    const size_t fixed = SZ_XBF + SZ_W1T + SZ_W2T + SZ_EO + SZ_G;
    const bool big = ws_size >= fixed + SZ_HBIG;

    // 1) conversions
    k_convert<<<(B_SZ * D_SZ / 8 + 255) / 256, 256, 0, stream>>>(x, x_bf, B_SZ * D_SZ / 8);
    dim3 tb(64, 8);
    k_transpose_convert<<<dim3(H_SZ / 64, D_SZ / 64, E_SZ), tb, 0, stream>>>(W1, W1T, D_SZ, H_SZ);
    k_transpose_convert<<<dim3(O_SZ / 64, H_SZ / 64, E_SZ), tb, 0, stream>>>(W2, W2T, H_SZ, O_SZ);

    // 2) gates
    k_gates<<<B_SZ / 4, 256, 0, stream>>>(x, Wg, Wgs, g_all);

    // 3) expert GEMMs (256x256 tiles; flat 1D grids, all % 8 == 0)
    if (big) {
        k_gemm4<<<(H_SZ / 256) * (B_SZ / 256) * E_SZ, 512, 0, stream>>>(
            x_bf, W1T, b1, h_buf, B_SZ, H_SZ, D_SZ,
            0LL, (long long)H_SZ * D_SZ, (long long)H_SZ, (long long)B_SZ * H_SZ, 0);
        k_gemm4<<<(O_SZ / 256) * (B_SZ / 256) * E_SZ, 512, 0, stream>>>(
            h_buf, W2T, b2, eo, B_SZ, O_SZ, H_SZ,
            (long long)B_SZ * H_SZ, (long long)O_SZ * H_SZ, (long long)O_SZ, (long long)B_SZ * O_SZ, 0);
    } else {
        for (int e = 0; e < E_SZ; ++e) {
            k_gemm4<<<(H_SZ / 256) * (B_SZ / 256), 512, 0, stream>>>(
                x_bf, W1T, b1, h_buf, B_SZ, H_SZ, D_SZ,
                0LL, (long long)H_SZ * D_SZ, (long long)H_SZ, 0LL, e);
            k_gemm4<<<(O_SZ / 256) * (B_SZ / 256), 512, 0, stream>>>(
                h_buf, W2T, b2, eo, B_SZ, O_SZ, H_SZ,
                0LL, (long long)O_SZ * H_SZ, (long long)O_SZ, (long long)B_SZ * O_SZ, e);
        }
    }

    // 4) combine
    k_combine<<<(B_SZ * O_SZ / 4) / 256, 256, 0, stream>>>(eo, g_all, out);
}

// Round 5
// 305.718 us; speedup vs baseline: 1.7742x; 1.0182x over previous
//
#include <hip/hip_runtime.h>
#include <hip/hip_bf16.h>
#include <stdint.h>

#define B_SZ 8192
#define D_SZ 1024
#define H_SZ 1024
#define O_SZ 512
#define E_SZ 8

typedef float f32x4 __attribute__((ext_vector_type(4)));
typedef __bf16 bf16x8 __attribute__((ext_vector_type(8)));

typedef __attribute__((address_space(1))) uint32_t gu32;
typedef __attribute__((address_space(3))) uint32_t lu32;

__device__ __forceinline__ unsigned short f2bf(float f) {
    union { __hip_bfloat16 h; unsigned short u; } c;
    c.h = __float2bfloat16(f);
    return c.u;
}
__device__ __forceinline__ float bf2f(unsigned short u) {
    union { float f; uint32_t u; } c;
    c.u = ((uint32_t)u) << 16;
    return c.f;
}

// ---------------- convert x (f32 -> bf16), 8 elems/thread ----------------
__global__ __launch_bounds__(256) void k_convert(const float* __restrict__ in,
                                                 unsigned short* __restrict__ out, int n8) {
    int i = blockIdx.x * 256 + threadIdx.x;
    if (i >= n8) return;
    const float4* p = (const float4*)in + (size_t)i * 2;
    float4 a = p[0], b = p[1];
    ushort4 lo, hi;
    lo.x = f2bf(a.x); lo.y = f2bf(a.y); lo.z = f2bf(a.z); lo.w = f2bf(a.w);
    hi.x = f2bf(b.x); hi.y = f2bf(b.y); hi.z = f2bf(b.z); hi.w = f2bf(b.w);
    ushort4* q = (ushort4*)out + (size_t)i * 2;
    q[0] = lo; q[1] = hi;
}

// ------- transpose+convert: in [E][R][C] f32 -> out [E][C][R] bf16 -------
// 64x64 tile: dst writes are 64 consecutive ushorts = 128 B full lines.
__global__ __launch_bounds__(512) void k_transpose_convert(const float* __restrict__ in,
                                                           unsigned short* __restrict__ out,
                                                           int R, int C) {
    __shared__ float tile[64][65];
    const float* src = in + (size_t)blockIdx.z * R * C;
    unsigned short* dst = out + (size_t)blockIdx.z * R * C;
    int c0 = blockIdx.x * 64, r0 = blockIdx.y * 64;
    int tx = threadIdx.x, ty = threadIdx.y;   // block (64,8)
#pragma unroll
    for (int rr = ty; rr < 64; rr += 8)
        tile[rr][tx] = src[(size_t)(r0 + rr) * C + c0 + tx];
    __syncthreads();
#pragma unroll
    for (int rr = ty; rr < 64; rr += 8)
        dst[(size_t)(c0 + rr) * R + r0 + tx] = f2bf(tile[tx][rr]);
}

// ---------------- gates: wave-parallel 20 logits/row + 3 softmaxes ----------------
__global__ __launch_bounds__(256) void k_gates(const float* __restrict__ x,
                                               const float* __restrict__ Wg,
                                               const float* __restrict__ Wgs,
                                               float* __restrict__ g_all) {
    const int wv = threadIdx.x >> 6;
    const int lane = threadIdx.x & 63;
    const int b = blockIdx.x * 4 + wv;
    const float* xr = x + (size_t)b * D_SZ;
    float acc[20];
#pragma unroll
    for (int j = 0; j < 20; ++j) acc[j] = 0.f;
    for (int d = lane; d < D_SZ; d += 64) {
        float xv = xr[d];
        const float* w0 = Wg + (size_t)d * 6;
        const float* w1 = Wg + (size_t)D_SZ * 6 + (size_t)d * 6;
        const float* ws = Wgs + (size_t)d * 8;
#pragma unroll
        for (int j = 0; j < 6; ++j) acc[j] += xv * w0[j];
#pragma unroll
        for (int j = 0; j < 6; ++j) acc[6 + j] += xv * w1[j];
#pragma unroll
        for (int j = 0; j < 8; ++j) acc[12 + j] += xv * ws[j];
    }
#pragma unroll
    for (int j = 0; j < 20; ++j) {
        float v = acc[j];
#pragma unroll
        for (int s = 32; s > 0; s >>= 1) v += __shfl_down(v, s, 64);
        acc[j] = v;
    }
    if (lane == 0) {
        float* g = g_all + (size_t)b * 20;
#pragma unroll
        for (int t = 0; t < 3; ++t) {
            int base = (t == 0) ? 0 : (t == 1 ? 6 : 12);
            int cnt  = (t == 2) ? 8 : 6;
            float m = -1e30f;
            for (int j = 0; j < cnt; ++j) m = fmaxf(m, acc[base + j]);
            float ex[8]; float sum = 0.f;
            for (int j = 0; j < cnt; ++j) { ex[j] = __expf(acc[base + j] - m); sum += ex[j]; }
            float inv = 1.f / sum;
            for (int j = 0; j < cnt; ++j) g[base + j] = ex[j] * inv;
        }
    }
}

// ---------------- 256x256 deep-pipelined bf16 GEMM, BK=32, 4 LDS buffers ----------------
// C[M][N] = relu(A[M][K] * Bt[N][K]^T + bias), bf16 in/out, f32 accum.
// 512 threads = 8 waves (2 M x 4 N); per-wave 128x64 output, acc[8][4] f32x4.
// LDS 128 KiB = 4 round-robin K-tile buffers x 32 KiB { A 256x32, B 256x32 }.
// Pipeline: during tile t -> stage glds for t+3, ds_read t+1's fragments into the
// alternate register set, MFMA on tile t's resident set. ONE barrier per tile.
// Compiler-managed lgkmcnt (waits land before next tile's first MFMA -> LDS
// service of t+1 hides under MFMA of t). Boundary guarantees tile t+2 landed:
// steady vmcnt(4), tail vmcnt(0) at t==NT-4.
// Race-freedom: reads of buf X (issued during X-1) drain before barrier(X-1+?);
// re-stage of buf X happens >=1 barrier later; stage target (t+3)%4 != {t,t+1}.
// Swizzle: physical 16B block = blk ^ ((row>>1)&3) -> 2-way (free) bank aliasing.
__global__ __launch_bounds__(512, 2) void k_gemm4(
    const unsigned short* __restrict__ A,
    const unsigned short* __restrict__ Bt,
    const float* __restrict__ bias,
    unsigned short* __restrict__ C,
    int M, int N, int K,
    long long sA, long long sB, long long sBias, long long sC, int e_base) {

    const int tid = threadIdx.x;
    const int lane = tid & 63, wid = tid >> 6;
    const int wr = wid >> 2, wc = wid & 3;       // 2 x 4 wave grid
    const int lr = lane & 15, lg = lane >> 4;

    // bijective XCD swizzle on flat grid (nwg % 8 == 0 for all launches here)
    const int nwg = gridDim.x;
    const int wg = blockIdx.x;
    const int swz = (wg & 7) * (nwg >> 3) + (wg >> 3);
    const int nx = N >> 8;
    const int my = M >> 8;
    const int bx = swz % nx;
    const int t1 = swz / nx;
    const int by = t1 % my;
    const int e  = t1 / my + e_base;

    A    += (size_t)((long long)e * sA);
    Bt   += (size_t)((long long)e * sB);
    bias += (size_t)((long long)e * sBias);
    C    += (size_t)((long long)e * sC);

    const int m0 = by * 256, n0 = bx * 256;

    __shared__ __align__(16) unsigned short lds[65536];   // 128 KiB
    char* ldsb = (char*)lds;

    // staging: 512 thr x 16 B = one 8 KiB half (128 rows x 32 cols bf16), linear dest.
    // physical (row, blk) holds source col-block blk ^ ((row>>1)&3)  (blk = 8-elem group)
    const int srow = tid >> 2;
    const int scol = (((tid & 3) ^ ((tid >> 3) & 3)) * 8);
    const int sdst = tid * 16;

    auto stageA = [&](int t) {
        const int bb = (t & 3) * 32768;
        const unsigned short* s0 = A + (size_t)(m0 + srow) * K + (t << 5) + scol;
        __builtin_amdgcn_global_load_lds((gu32*)s0, (lu32*)(ldsb + bb + sdst), 16, 0, 0);
        __builtin_amdgcn_global_load_lds((gu32*)(s0 + (size_t)128 * K),
                                         (lu32*)(ldsb + bb + 8192 + sdst), 16, 0, 0);
    };
    auto stageB = [&](int t) {
        const int bb = (t & 3) * 32768 + 16384;
        const unsigned short* s0 = Bt + (size_t)(n0 + srow) * K + (t << 5) + scol;
        __builtin_amdgcn_global_load_lds((gu32*)s0, (lu32*)(ldsb + bb + sdst), 16, 0, 0);
        __builtin_amdgcn_global_load_lds((gu32*)(s0 + (size_t)128 * K),
                                         (lu32*)(ldsb + bb + 8192 + sdst), 16, 0, 0);
    };

    // fragment read constants (byte offsets); swizzle term depends only on lr
    const int cblk = (lg ^ ((lr >> 1) & 3)) * 16;
    const int aoff = wr * 8192 + lr * 64 + cblk;
    const int boff = 16384 + (wc >> 1) * 8192 + (wc & 1) * 4096 + lr * 64 + cblk;

    // frags: f[0..7] = A rows 0-7 (m-frags), f[8..11] = B cols 0-3 (n-frags)
    auto loadf = [&](bf16x8* f, int bb) {
#pragma unroll
        for (int i = 0; i < 8; ++i)
            f[i] = *(const bf16x8*)(ldsb + bb + aoff + i * 1024);
#pragma unroll
        for (int j = 0; j < 4; ++j)
            f[8 + j] = *(const bf16x8*)(ldsb + bb + boff + j * 1024);
    };

    f32x4 acc[8][4];
#pragma unroll
    for (int i = 0; i < 8; ++i)
#pragma unroll
        for (int j = 0; j < 4; ++j)
            acc[i][j] = f32x4{0.f, 0.f, 0.f, 0.f};

    auto domfma = [&](const bf16x8* f) {
        __builtin_amdgcn_s_setprio(1);
#pragma unroll
        for (int i = 0; i < 8; ++i)
#pragma unroll
            for (int j = 0; j < 4; ++j)
                acc[i][j] = __builtin_amdgcn_mfma_f32_16x16x32_bf16(f[i], f[8 + j], acc[i][j], 0, 0, 0);
        __builtin_amdgcn_s_setprio(0);
    };

    const int NT = K >> 5;   // 32 (even, >= 8)

    // prologue: stage tiles 0,1,2 (12 glds); wait tiles 0,1 landed (leave tile 2's 4)
    stageA(0); stageB(0); stageA(1); stageB(1); stageA(2); stageB(2);
    asm volatile("s_waitcnt vmcnt(4)" ::: "memory");
    asm volatile("s_barrier" ::: "memory");

    bf16x8 fA[12], fB[12];
    loadf(fA, 0);

    for (int t = 0; t < NT; t += 2) {
        // ---- even tile t: consume fA(t); load fB(t+1); stage t+3 ----
        if (t + 3 < NT) { stageA(t + 3); stageB(t + 3); }
        loadf(fB, ((t + 1) & 3) * 32768);        // buf t+1 landed (prev boundary)
        domfma(fA);
        // boundary: need tile t+2 landed (read next half). outstanding: t+2, t+3 stages.
        if (t + 3 < NT)      { asm volatile("s_waitcnt vmcnt(4)" ::: "memory"); }
        else if (t + 2 < NT) { asm volatile("s_waitcnt vmcnt(0)" ::: "memory"); }
        asm volatile("s_barrier" ::: "memory");

        // ---- odd tile t+1: consume fB(t+1); load fA(t+2); stage t+4 ----
        if (t + 4 < NT) { stageA(t + 4); stageB(t + 4); }
        if (t + 2 < NT) loadf(fA, ((t + 2) & 3) * 32768);
        domfma(fB);
        // boundary: need tile t+3 landed. outstanding: t+3, t+4 stages.
        if (t + 4 < NT)      { asm volatile("s_waitcnt vmcnt(4)" ::: "memory"); }
        else if (t + 3 < NT) { asm volatile("s_waitcnt vmcnt(0)" ::: "memory"); }
        asm volatile("s_barrier" ::: "memory");
    }

    // ---- epilogue: bias + relu -> LDS-staged bf16 tile -> coalesced dwordx4 stores ----
    // LDS dead: all glds drained (vmcnt(0) at t==NT-4 boundary), all ds_reads
    // consumed before each wave's final barrier arrival.
    unsigned short* ct = (unsigned short*)ldsb;
#pragma unroll
    for (int j = 0; j < 4; ++j) {
        const int nn = wc * 64 + j * 16 + lr;
        const float bv = bias[n0 + nn];
#pragma unroll
        for (int i = 0; i < 8; ++i) {
            const int mb = wr * 128 + i * 16 + lg * 4;
#pragma unroll
            for (int r = 0; r < 4; ++r) {
                float v = fmaxf(acc[i][j][r] + bv, 0.f);
                ct[(size_t)(mb + r) * 256 + nn] = f2bf(v);
            }
        }
    }
    __syncthreads();
#pragma unroll
    for (int it = 0; it < 16; ++it) {
        const int row = it * 16 + (tid >> 5);
        const int colE = (tid & 31) * 8;
        *(int4*)(&C[(size_t)(m0 + row) * N + n0 + colE]) =
            *(const int4*)(ldsb + it * 8192 + (size_t)tid * 16);
    }
}

// ---------------- combine: out[b][t][o], 4 o's per thread ----------------
__global__ __launch_bounds__(256) void k_combine(const unsigned short* __restrict__ eo,
                                                 const float* __restrict__ g_all,
                                                 float* __restrict__ out) {
    int idx4 = blockIdx.x * 256 + threadIdx.x;    // over B*O/4
    int b = idx4 >> 7;                            // O/4 = 128
    int o4 = (idx4 & 127) * 4;
    const float* g = g_all + (size_t)b * 20;
    float v[E_SZ][4];
#pragma unroll
    for (int e = 0; e < E_SZ; ++e) {
        ushort4 u = *(const ushort4*)(eo + (size_t)e * B_SZ * O_SZ + (size_t)b * O_SZ + o4);
        v[e][0] = bf2f(u.x); v[e][1] = bf2f(u.y); v[e][2] = bf2f(u.z); v[e][3] = bf2f(u.w);
    }
    float4 r0, r1, r2;
    float* p0 = (float*)&r0; float* p1 = (float*)&r1; float* p2 = (float*)&r2;
#pragma unroll
    for (int c = 0; c < 4; ++c) {
        p0[c] = g[0] * v[0][c] + g[1] * v[1][c] + g[2] * v[4][c] + g[3] * v[5][c]
              + g[4] * v[6][c] + g[5] * v[7][c];
        p1[c] = g[6] * v[2][c] + g[7] * v[3][c] + g[8] * v[4][c] + g[9] * v[5][c]
              + g[10] * v[6][c] + g[11] * v[7][c];
        float s = 0.f;
#pragma unroll
        for (int e = 0; e < E_SZ; ++e) s += g[12 + e] * v[e][c];
        p2[c] = s;
    }
    size_t ob = (size_t)b * (3 * O_SZ) + o4;
    *(float4*)(out + ob) = r0;
    *(float4*)(out + ob + O_SZ) = r1;
    *(float4*)(out + ob + 2 * O_SZ) = r2;
}

extern "C" void kernel_launch(void* const* d_in, const int* in_sizes, int n_in,
                              void* d_out, int out_size, void* d_ws, size_t ws_size,
                              hipStream_t stream) {
    const float* x   = (const float*)d_in[0];
    const float* W1  = (const float*)d_in[1];
    const float* b1  = (const float*)d_in[2];
    const float* W2  = (const float*)d_in[3];
    const float* b2  = (const float*)d_in[4];
    const float* Wg  = (const float*)d_in[5];
    const float* Wgs = (const float*)d_in[6];
    float* out = (float*)d_out;

    char* ws = (char*)d_ws;
    const size_t SZ_XBF  = (size_t)B_SZ * D_SZ * 2;           // 16 MB
    const size_t SZ_W1T  = (size_t)E_SZ * H_SZ * D_SZ * 2;    // 16 MB
    const size_t SZ_W2T  = (size_t)E_SZ * O_SZ * H_SZ * 2;    // 8 MB
    const size_t SZ_EO   = (size_t)E_SZ * B_SZ * O_SZ * 2;    // 64 MB
    const size_t SZ_G    = (size_t)B_SZ * 20 * 4;             // 640 KB
    const size_t SZ_HBIG = (size_t)E_SZ * B_SZ * H_SZ * 2;    // 128 MB

    unsigned short* x_bf = (unsigned short*)ws;              ws += SZ_XBF;
    unsigned short* W1T  = (unsigned short*)ws;              ws += SZ_W1T;
    unsigned short* W2T  = (unsigned short*)ws;              ws += SZ_W2T;
    unsigned short* eo   = (unsigned short*)ws;              ws += SZ_EO;
    float* g_all         = (float*)ws;                       ws += SZ_G;
    unsigned short* h_buf = (unsigned short*)ws;

    const size_t fixed = SZ_XBF + SZ_W1T + SZ_W2T + SZ_EO + SZ_G;
    const bool big = ws_size >= fixed + SZ_HBIG;

    // 1) conversions
    k_convert<<<(B_SZ * D_SZ / 8 + 255) / 256, 256, 0, stream>>>(x, x_bf, B_SZ * D_SZ / 8);
    dim3 tb(64, 8);
    k_transpose_convert<<<dim3(H_SZ / 64, D_SZ / 64, E_SZ), tb, 0, stream>>>(W1, W1T, D_SZ, H_SZ);
    k_transpose_convert<<<dim3(O_SZ / 64, H_SZ / 64, E_SZ), tb, 0, stream>>>(W2, W2T, H_SZ, O_SZ);

    // 2) gates
    k_gates<<<B_SZ / 4, 256, 0, stream>>>(x, Wg, Wgs, g_all);

    // 3) expert GEMMs (256x256 tiles; flat 1D grids, all % 8 == 0)
    if (big) {
        k_gemm4<<<(H_SZ / 256) * (B_SZ / 256) * E_SZ, 512, 0, stream>>>(
            x_bf, W1T, b1, h_buf, B_SZ, H_SZ, D_SZ,
            0LL, (long long)H_SZ * D_SZ, (long long)H_SZ, (long long)B_SZ * H_SZ, 0);
        k_gemm4<<<(O_SZ / 256) * (B_SZ / 256) * E_SZ, 512, 0, stream>>>(
            h_buf, W2T, b2, eo, B_SZ, O_SZ, H_SZ,
            (long long)B_SZ * H_SZ, (long long)O_SZ * H_SZ, (long long)O_SZ, (long long)B_SZ * O_SZ, 0);
    } else {
        for (int e = 0; e < E_SZ; ++e) {
            k_gemm4<<<(H_SZ / 256) * (B_SZ / 256), 512, 0, stream>>>(
                x_bf, W1T, b1, h_buf, B_SZ, H_SZ, D_SZ,
                0LL, (long long)H_SZ * D_SZ, (long long)H_SZ, 0LL, e);
            k_gemm4<<<(O_SZ / 256) * (B_SZ / 256), 512, 0, stream>>>(
                h_buf, W2T, b2, eo, B_SZ, O_SZ, H_SZ,
                0LL, (long long)O_SZ * H_SZ, (long long)O_SZ, (long long)B_SZ * O_SZ, e);
        }
    }

    // 4) combine
    k_combine<<<(B_SZ * O_SZ / 4) / 256, 256, 0, stream>>>(eo, g_all, out);
}